// Round 11
// baseline (153.518 us; speedup 1.0000x reference)
//
#include <hip/hip_runtime.h>
#include <stdint.h>

// ---------------------------------------------------------------------------
// Problem constants (from reference)
// ---------------------------------------------------------------------------
#define C_RMIN 100000.0f
#define C_RMAX 10000000.0f
#define C_CMIN 1e-07f
#define C_CMAX 1e-04f
#define C_DT   0.1f
#define C_EPS  0.05f
#define C_COUP 0.2f

typedef __attribute__((ext_vector_type(8))) short bf16x8;
typedef __attribute__((ext_vector_type(4))) float floatx4;

// ---------------------------------------------------------------------------
// Threefry-2x32 (exact JAX semantics). Host+device.
// ---------------------------------------------------------------------------
__host__ __device__ inline void tf2x32(uint32_t k0, uint32_t k1,
                                       uint32_t& x0, uint32_t& x1) {
  uint32_t ks2 = k0 ^ k1 ^ 0x1BD11BDAu;
  uint32_t a = x0 + k0, b = x1 + k1;
#define TFR(r) a += b; b = (b << (r)) | (b >> (32 - (r))); b ^= a;
  TFR(13) TFR(15) TFR(26) TFR(6)
  a += k1;  b += ks2 + 1u;
  TFR(17) TFR(29) TFR(16) TFR(24)
  a += ks2; b += k0 + 2u;
  TFR(13) TFR(15) TFR(26) TFR(6)
  a += k0;  b += k1 + 3u;
  TFR(17) TFR(29) TFR(16) TFR(24)
  a += k1;  b += ks2 + 4u;
  TFR(13) TFR(15) TFR(26) TFR(6)
  a += ks2; b += k0 + 5u;
#undef TFR
  x0 = a; x1 = b;
}

// jax.random.uniform element e, PARTITIONABLE threefry (jax>=0.5 default):
// one block per element, counter = (0, e), bits = out0 ^ out1.
__device__ inline float unif01(uint32_t k0, uint32_t k1, uint32_t e) {
  uint32_t x0 = 0u, x1 = e;
  tf2x32(k0, k1, x0, x1);
  uint32_t bits = x0 ^ x1;
  return __uint_as_float((bits >> 9) | 0x3F800000u) - 1.0f;
}

__device__ inline float theta_eff(float t) {
  t = fminf(fmaxf(t, -10.0f), 10.0f);
  return (fabsf(t) < 0.01f) ? 0.0f : t;
}

__device__ inline float sigmoidf(float x) { return 1.0f / (1.0f + expf(-x)); }

__device__ inline float noise_mul(float u) { return (u * 2.0f - 1.0f) * C_EPS + 1.0f; }

// ---------------------------------------------------------------------------
// PREP (single prep kernel, heavy-work-first, ~9.6 KB LDS):
//   bids [0,32)     -> denom2 partials (64-way j split)
//   bids [32,160)   -> a1 (first pmac), S1eff regenerated in-block
//   bids [160,1184) -> beta12 interleaved; 4 t's per thread (2x finer than
//                      R10 -> ~5 waves/SIMD for the threefry-issue-bound part)
// ---------------------------------------------------------------------------
__global__ __launch_bounds__(256) void prep_kernel(
    const float* __restrict__ Rlf, const float* __restrict__ Clf,
    const float* __restrict__ theta1, const float* __restrict__ theta2,
    const float* __restrict__ x,
    float* __restrict__ beta12, float* __restrict__ a1,
    float* __restrict__ denom2p,
    uint32_t k1a, uint32_t k1b, uint32_t k4a, uint32_t k4b,
    uint32_t kR1a, uint32_t kR1b, uint32_t kC1a, uint32_t kC1b,
    uint32_t kM1a, uint32_t kM1b,
    uint32_t kR2a, uint32_t kR2b, uint32_t kC2a, uint32_t kC2b,
    uint32_t kM2a, uint32_t kM2b) {
  __shared__ float red[256];
  __shared__ float vsm[34 * 32];
  __shared__ float S1s[33 * 32];
  int bid = blockIdx.x;
  int tid = threadIdx.x;
  if (bid < 32) {
    // ---- denom2 partials: denom2p[(n*8+p)*32+o] ----
    int n = bid >> 3, p = bid & 7;
    int o = tid & 31;
    int jc = tid >> 5;                  // 0..7
    int j0 = p * 8 + jc;                // 0..63
    float part = 0.0f;
    for (int j = j0; j < 1058; j += 64) {
      float t = theta_eff(theta2[j * 32 + o]);
      float u = unif01(k4a, k4b, (uint32_t)((n * 1058 + j) * 32 + o));
      part += fabsf(t * noise_mul(u));
    }
    red[jc * 32 + o] = part;
    __syncthreads();
    if (jc == 0) {
      float s = 0.0f;
      for (int q = 0; q < 8; ++q) s += red[q * 32 + o];
      denom2p[(n * 8 + p) * 32 + o] = s;
    }
  } else if (bid < 160) {
    // ---- a1[n][b][o][t], S1eff regenerated in-block, acc in registers ----
    int blk = bid - 32;
    int n = blk >> 5, b = blk & 31;
    int o = tid & 31, mq = tid >> 5;    // mq 0..7
    float dp = 0.0f;
    for (int m = mq; m < 34; m += 8) {
      float t = theta_eff(theta1[m * 32 + o]);
      float v = t * noise_mul(unif01(k1a, k1b, (uint32_t)((n * 34 + m) * 32 + o)));
      vsm[m * 32 + o] = v;
      dp += fabsf(v);
    }
    red[mq * 32 + o] = dp;
    __syncthreads();
    for (int idx = tid; idx < 33 * 32; idx += 256) {
      int oo = idx & 31;
      float den = 1e-10f;
#pragma unroll
      for (int q = 0; q < 8; ++q) den += red[q * 32 + oo];
      S1s[idx] = vsm[idx] / den;
    }
    __syncthreads();
    const float* xp = x + (size_t)((n * 32 + b) * 32) * 256;
    float acc[32];
#pragma unroll
    for (int oo = 0; oo < 32; ++oo) acc[oo] = S1s[32 * 32 + oo];
    for (int m = 0; m < 32; ++m) {
      float xm = xp[m * 256 + tid];
#pragma unroll
      for (int oo = 0; oo < 32; ++oo) acc[oo] += xm * S1s[m * 32 + oo];
    }
    float* ap = a1 + (size_t)((n * 32 + b) * 32) * 256;
#pragma unroll
    for (int oo = 0; oo < 32; ++oo)
      ap[oo * 256 + tid] = 0.05f + 0.5f * tanhf((acc[oo] - 0.3f) * 3.0f);
  } else {
    // ---- beta12: thread handles 4 t's for fixed (n,k), both cascades ----
    int u = (bid - 160) * 256 + tid;    // [0, 262144)
    int k = u & 1023;
    int tc = (u >> 10) & 63;
    int n = u >> 16;                    // 0..3
    float Rt1 = sigmoidf(Rlf[k * 2 + 0]) * (C_RMAX - C_RMIN) + C_RMIN;
    float Ct1 = sigmoidf(Clf[k * 2 + 0]) * (C_CMAX - C_CMIN) + C_CMIN;
    float Rt2 = sigmoidf(Rlf[k * 2 + 1]) * (C_RMAX - C_RMIN) + C_RMIN;
    float Ct2 = sigmoidf(Clf[k * 2 + 1]) * (C_CMAX - C_CMIN) + C_CMIN;
#pragma unroll
    for (int it = 0; it < 4; ++it) {
      int t = tc * 4 + it;
      uint32_t e = (uint32_t)((t * 1024 + k) * 4 + n);
      float nR1 = noise_mul(unif01(kR1a, kR1b, e));
      float nC1 = noise_mul(unif01(kC1a, kC1b, e));
      float mu1 = unif01(kM1a, kM1b, e) * C_COUP + 1.0f;
      float rc1 = mu1 * (Rt1 * nR1) * (Ct1 * nC1);
      float nR2 = noise_mul(unif01(kR2a, kR2b, e));
      float nC2 = noise_mul(unif01(kC2a, kC2b, e));
      float mu2 = unif01(kM2a, kM2b, e) * C_COUP + 1.0f;
      float rc2 = mu2 * (Rt2 * nR2) * (Ct2 * nC2);
      float2 bb = { rc1 / (rc1 + C_DT), rc2 / (rc2 + C_DT) };
      *(float2*)&beta12[(size_t)(((n * 256 + t) * 1024) + k) * 2] = bb;
    }
  }
}

// ---------------------------------------------------------------------------
// FK9: fk8 + register prefetch of next chunk's beta/x loads.
// The producer's 16-step chunk is a serial FMA chain; without prefetch each
// step stalls on an in-loop global load (~200 cyc L2) -> ~3200 cyc/chunk of
// unhidden latency (the real reason fk6..fk8 sat at ~40 us — NOT issue count).
// Prefetch chunk c+1 into registers while chunk c's chain executes.
// Grid/swizzle unchanged: bid = b*32 + n*8 + e; 192 thr (2 producer waves +
// 1 MFMA consumer wave); single RNE bf16 y-plane.
// ---------------------------------------------------------------------------
#define YP 136                      // uint16 per t-row (128 + 8 pad)
#define YPLANE (16 * YP)            // one chunk plane (uint16 count)

__global__ __launch_bounds__(192, 3) void fk9_kernel(
    const float* __restrict__ a1, const float* __restrict__ theta2,
    const float* __restrict__ denom2p,
    const float* __restrict__ beta12, float* __restrict__ zpart,
    uint32_t k01a, uint32_t k01b, uint32_t k02a, uint32_t k02b,
    uint32_t k4a, uint32_t k4b) {
  int bid = blockIdx.x;
  int g = bid & 31;                 // g = n*8 + e
  int b = bid >> 5;
  int n = g >> 3, e = g & 7;
  int nb = n * 32 + b;
  int tid = threadIdx.x;

  __shared__ __align__(16) uint16_t yh[2 * YPLANE];   // 8704 B
  __shared__ __align__(16) short wf[8 * 512];         // 8192 B
  __shared__ float sden[32];

  const float* a1nb = a1 + (size_t)nb * 8192;
  const float* bp = beta12 + (size_t)n * 524288 + e * 256;
  float* zout = zpart + (size_t)bid * 8192;

  if (tid < 32) {
    float d = 1e-10f;
#pragma unroll
    for (int q = 0; q < 8; ++q) d += denom2p[(n * 8 + q) * 32 + tid];
    sden[tid] = d;
  }
  __syncthreads();

  float s1 = 0.0f, s2 = 0.0f;
  int cc = 0;
  float2 breg[16];
  float xreg[16];

  // W build spread over all 192 threads: 4096 weights, 22 iters
  for (int it = 0; it < 22; ++it) {
    int widx = it * 192 + tid;
    if (widx < 4096) {
      int j = widx & 7;
      int lane_ = (widx >> 3) & 63;
      int ot = (widx >> 9) & 1;
      int ks = widx >> 10;                  // 0..3
      int sub = ((lane_ >> 4) << 3) + j;    // k within 32-chunk
      int jrow = (e * 4 + ks) * 33 + 1 + sub;
      int oo = ot * 16 + (lane_ & 15);
      float th = theta_eff(theta2[jrow * 32 + oo]);
      float u = unif01(k4a, k4b, (uint32_t)((n * 1058 + jrow) * 32 + oo));
      float w = th * noise_mul(u) / sden[oo];
      uint32_t wb = __float_as_uint(w);
      uint32_t hi = (wb + 0x7FFFu + ((wb >> 16) & 1u)) >> 16;   // RNE bf16
      wf[(ks * 2 + ot) * 512 + lane_ * 8 + j] = (short)(uint16_t)hi;
    }
  }
  if (tid < 128) {
    int k = e * 128 + tid;
    uint32_t e0 = (uint32_t)((k * 4 + n) * 32 + b);
    s1 = unif01(k01a, k01b, e0);
    s2 = unif01(k02a, k02b, e0);
    cc = k >> 5;
    // prologue: prefetch chunk 0
#pragma unroll
    for (int it = 0; it < 16; ++it) {
      breg[it] = *(const float2*)&bp[(size_t)it * 2048 + tid * 2];
      xreg[it] = a1nb[cc * 256 + it];
    }
  }
  __syncthreads();

  for (int c = 0; c <= 16; ++c) {
    if (tid < 128) {
      if (c < 16) {
        // issue next chunk's loads FIRST so they fly over this chunk's chain
        float2 bnext[16];
        float xnext[16];
        if (c < 15) {
#pragma unroll
          for (int it = 0; it < 16; ++it) {
            int t = (c + 1) * 16 + it;
            bnext[it] = *(const float2*)&bp[(size_t)t * 2048 + tid * 2];
            xnext[it] = a1nb[cc * 256 + t];
          }
        }
        uint16_t* yhb = yh + (c & 1) * YPLANE;
#pragma unroll
        for (int it = 0; it < 16; ++it) {
          uint32_t sb = __float_as_uint(s2);
          uint32_t r = (sb + 0x7FFFu + ((sb >> 16) & 1u)) >> 16;  // RNE bf16
          yhb[it * YP + tid] = (uint16_t)r;
          float2 bb = breg[it];
          float xv = xreg[it];
          s2 = bb.y * (s2 - s1) + s1;     // cascade 2 eats pre-update s1
          s1 = bb.x * (s1 - xv) + xv;
        }
        if (c < 15) {
#pragma unroll
          for (int it = 0; it < 16; ++it) { breg[it] = bnext[it]; xreg[it] = xnext[it]; }
        }
      }
    } else if (c >= 1) {
      int lane = tid - 128;
      int tc = lane & 15, q = lane >> 4;
      const uint16_t* yhr = yh + ((c - 1) & 1) * YPLANE + tc * YP + q * 8;
      floatx4 acc0a = {0,0,0,0}, acc0b = {0,0,0,0};
      floatx4 acc1a = {0,0,0,0}, acc1b = {0,0,0,0};
#pragma unroll
      for (int ks = 0; ks < 4; ++ks) {
        bf16x8 ah = *(const bf16x8*)(yhr + ks * 32);
        bf16x8 bh0 = *(const bf16x8*)&wf[(ks * 2 + 0) * 512 + lane * 8];
        bf16x8 bh1 = *(const bf16x8*)&wf[(ks * 2 + 1) * 512 + lane * 8];
        if (ks & 1) {
          acc0b = __builtin_amdgcn_mfma_f32_16x16x32_bf16(ah, bh0, acc0b, 0, 0, 0);
          acc1b = __builtin_amdgcn_mfma_f32_16x16x32_bf16(ah, bh1, acc1b, 0, 0, 0);
        } else {
          acc0a = __builtin_amdgcn_mfma_f32_16x16x32_bf16(ah, bh0, acc0a, 0, 0, 0);
          acc1a = __builtin_amdgcn_mfma_f32_16x16x32_bf16(ah, bh1, acc1a, 0, 0, 0);
        }
      }
      int t0 = (c - 1) * 16;
      floatx4 r0 = acc0a + acc0b;
      floatx4 r1 = acc1a + acc1b;
      // D layout: col = lane&15 (=o within tile), row = q*4 + reg (=t_local)
      *(floatx4*)&zout[tc * 256 + t0 + q * 4] = r0;
      *(floatx4*)&zout[(16 + tc) * 256 + t0 + q * 4] = r1;
    }
    __syncthreads();
  }
}

// ---------------------------------------------------------------------------
// CB3: combine 8 K-eighths + direct-channel term + bias + activation.
// zpart slices for nb=(n,b) at bid = b*32 + n*8 + e -> contiguous 8 slices.
// ---------------------------------------------------------------------------
__global__ __launch_bounds__(256) void cb3_kernel(
    const float* __restrict__ a1, const float* __restrict__ theta2,
    const float* __restrict__ denom2p,
    const float* __restrict__ zpart, float* __restrict__ out,
    uint32_t k4a, uint32_t k4b) {
  int nb = blockIdx.x;
  int n = nb >> 5, b = nb & 31;
  int t = threadIdx.x;
  __shared__ float xs[32][256];
  __shared__ float wd[33 * 32];   // r<32: direct channel c=r (j=r*33); r=32: bias (j=1056)
  __shared__ float sden[32];
  if (t < 32) {
    float d = 1e-10f;
#pragma unroll
    for (int q = 0; q < 8; ++q) d += denom2p[(n * 8 + q) * 32 + t];
    sden[t] = d;
  }
  const float* a1nb = a1 + (size_t)nb * 8192;
  for (int c = 0; c < 32; ++c) xs[c][t] = a1nb[c * 256 + t];
  __syncthreads();
  for (int idx = t; idx < 33 * 32; idx += 256) {
    int r = idx >> 5, oo = idx & 31;
    int j = (r < 32) ? r * 33 : 1056;
    float th = theta_eff(theta2[j * 32 + oo]);
    float u = unif01(k4a, k4b, (uint32_t)((n * 1058 + j) * 32 + oo));
    wd[idx] = th * noise_mul(u) / sden[oo];
  }
  __syncthreads();
  const float* zp = zpart + (size_t)(b * 32 + n * 8) * 8192;
  float* op = out + (size_t)nb * 8192;
  for (int o = 0; o < 32; ++o) {
    float z = wd[32 * 32 + o];
#pragma unroll
    for (int c = 0; c < 32; ++c) z += xs[c][t] * wd[c * 32 + o];
#pragma unroll
    for (int e = 0; e < 8; ++e) z += zp[e * 8192 + o * 256 + t];
    op[o * 256 + t] = 0.05f + 0.5f * tanhf((z - 0.3f) * 3.0f);
  }
}

// ---------------------------------------------------------------------------
// Launch
// ---------------------------------------------------------------------------
struct KeyPair { uint32_t a, b; };

// jax.random.split(key, 4), PARTITIONABLE (foldlike): key_i = threefry(key,(0,i))
static inline void split4_host(KeyPair key, KeyPair out[4]) {
  for (uint32_t i = 0; i < 4; ++i) {
    uint32_t x0 = 0u, x1 = i;
    tf2x32(key.a, key.b, x0, x1);
    out[i] = {x0, x1};
  }
}

extern "C" void kernel_launch(void* const* d_in, const int* in_sizes, int n_in,
                              void* d_out, int out_size, void* d_ws, size_t ws_size,
                              hipStream_t stream) {
  const float* x   = (const float*)d_in[0];   // (4,32,32,256)
  const float* th1 = (const float*)d_in[1];   // (34,32)
  const float* th2 = (const float*)d_in[2];   // (1058,32)
  const float* Rlf = (const float*)d_in[3];   // (32,32,2)
  const float* Clf = (const float*)d_in[4];   // (32,32,2)
  float* out = (float*)d_out;                 // (4,32,32,256)
  float* ws = (float*)d_ws;

  // workspace layout (floats)
  float* den2p  = ws;                  // 1024
  float* a1     = ws + 1024;           // 1048576
  float* beta12 = ws + 1049600;        // 2097152 (interleaved b1,b2)
  float* zpart  = ws + 3146752;        // 8388608 (1024 blocks x 8192) ~46 MB

  KeyPair root{0u, 42u};
  KeyPair kk[4];  split4_host(root, kk);     // {k1, k2, k3, k4}
  KeyPair f1[4];  split4_host(kk[1], f1);    // {kR1, kC1, kmu1, k01}
  KeyPair f2[4];  split4_host(kk[2], f2);    // {kR2, kC2, kmu2, k02}

  prep_kernel<<<dim3(1184), dim3(256), 0, stream>>>(
      Rlf, Clf, th1, th2, x, beta12, a1, den2p,
      kk[0].a, kk[0].b, kk[3].a, kk[3].b,
      f1[0].a, f1[0].b, f1[1].a, f1[1].b, f1[2].a, f1[2].b,
      f2[0].a, f2[0].b, f2[1].a, f2[1].b, f2[2].a, f2[2].b);
  fk9_kernel<<<dim3(1024), dim3(192), 0, stream>>>(
      a1, th2, den2p, beta12, zpart,
      f1[3].a, f1[3].b, f2[3].a, f2[3].b, kk[3].a, kk[3].b);
  cb3_kernel<<<dim3(128), dim3(256), 0, stream>>>(
      a1, th2, den2p, zpart, out, kk[3].a, kk[3].b);
}

// Round 12
// 134.906 us; speedup vs baseline: 1.1380x; 1.1380x over previous
//
#include <hip/hip_runtime.h>
#include <stdint.h>

// ---------------------------------------------------------------------------
// Problem constants (from reference)
// ---------------------------------------------------------------------------
#define C_RMIN 100000.0f
#define C_RMAX 10000000.0f
#define C_CMIN 1e-07f
#define C_CMAX 1e-04f
#define C_DT   0.1f
#define C_EPS  0.05f
#define C_COUP 0.2f

typedef __attribute__((ext_vector_type(8))) short bf16x8;
typedef __attribute__((ext_vector_type(4))) float floatx4;

// ---------------------------------------------------------------------------
// Threefry-2x32 (exact JAX semantics). Host+device.
// ---------------------------------------------------------------------------
__host__ __device__ inline void tf2x32(uint32_t k0, uint32_t k1,
                                       uint32_t& x0, uint32_t& x1) {
  uint32_t ks2 = k0 ^ k1 ^ 0x1BD11BDAu;
  uint32_t a = x0 + k0, b = x1 + k1;
#define TFR(r) a += b; b = (b << (r)) | (b >> (32 - (r))); b ^= a;
  TFR(13) TFR(15) TFR(26) TFR(6)
  a += k1;  b += ks2 + 1u;
  TFR(17) TFR(29) TFR(16) TFR(24)
  a += ks2; b += k0 + 2u;
  TFR(13) TFR(15) TFR(26) TFR(6)
  a += k0;  b += k1 + 3u;
  TFR(17) TFR(29) TFR(16) TFR(24)
  a += k1;  b += ks2 + 4u;
  TFR(13) TFR(15) TFR(26) TFR(6)
  a += ks2; b += k0 + 5u;
#undef TFR
  x0 = a; x1 = b;
}

// jax.random.uniform element e, PARTITIONABLE threefry (jax>=0.5 default):
// one block per element, counter = (0, e), bits = out0 ^ out1.
__device__ inline float unif01(uint32_t k0, uint32_t k1, uint32_t e) {
  uint32_t x0 = 0u, x1 = e;
  tf2x32(k0, k1, x0, x1);
  uint32_t bits = x0 ^ x1;
  return __uint_as_float((bits >> 9) | 0x3F800000u) - 1.0f;
}

__device__ inline float theta_eff(float t) {
  t = fminf(fmaxf(t, -10.0f), 10.0f);
  return (fabsf(t) < 0.01f) ? 0.0f : t;
}

__device__ inline float sigmoidf(float x) { return 1.0f / (1.0f + expf(-x)); }

__device__ inline float noise_mul(float u) { return (u * 2.0f - 1.0f) * C_EPS + 1.0f; }

// ---------------------------------------------------------------------------
// PREP (single prep kernel, heavy-work-first):
//   bids [0,32)    -> denom2 partials (64-way j split)
//   bids [32,160)  -> a1 (first pmac), S1eff regenerated in-block
//   bids [160,672) -> beta12 interleaved (both cascades per thread, 8 t's)
//   bids [672,800) -> wbuf: RAW filter weights theta*noise as RNE bf16 in
//                     MFMA-fragment layout (NO /sden — the division commutes
//                     past the MFMA k-sum; cb applies 1/sden[o] once).
// ---------------------------------------------------------------------------
__global__ __launch_bounds__(256) void prep_kernel(
    const float* __restrict__ Rlf, const float* __restrict__ Clf,
    const float* __restrict__ theta1, const float* __restrict__ theta2,
    const float* __restrict__ x,
    float* __restrict__ beta12, float* __restrict__ a1,
    float* __restrict__ denom2p, uint16_t* __restrict__ wbuf,
    uint32_t k1a, uint32_t k1b, uint32_t k4a, uint32_t k4b,
    uint32_t kR1a, uint32_t kR1b, uint32_t kC1a, uint32_t kC1b,
    uint32_t kM1a, uint32_t kM1b,
    uint32_t kR2a, uint32_t kR2b, uint32_t kC2a, uint32_t kC2b,
    uint32_t kM2a, uint32_t kM2b) {
  __shared__ float red[256];
  __shared__ float vsm[34 * 32];
  __shared__ float S1s[33 * 32];
  int bid = blockIdx.x;
  int tid = threadIdx.x;
  if (bid < 32) {
    // ---- denom2 partials: denom2p[(n*8+p)*32+o] ----
    int n = bid >> 3, p = bid & 7;
    int o = tid & 31;
    int jc = tid >> 5;                  // 0..7
    int j0 = p * 8 + jc;                // 0..63
    float part = 0.0f;
    for (int j = j0; j < 1058; j += 64) {
      float t = theta_eff(theta2[j * 32 + o]);
      float u = unif01(k4a, k4b, (uint32_t)((n * 1058 + j) * 32 + o));
      part += fabsf(t * noise_mul(u));
    }
    red[jc * 32 + o] = part;
    __syncthreads();
    if (jc == 0) {
      float s = 0.0f;
      for (int q = 0; q < 8; ++q) s += red[q * 32 + o];
      denom2p[(n * 8 + p) * 32 + o] = s;
    }
  } else if (bid < 160) {
    // ---- a1[n][b][o][t], S1eff regenerated in-block, acc in registers ----
    int blk = bid - 32;
    int n = blk >> 5, b = blk & 31;
    int o = tid & 31, mq = tid >> 5;    // mq 0..7
    float dp = 0.0f;
    for (int m = mq; m < 34; m += 8) {
      float t = theta_eff(theta1[m * 32 + o]);
      float v = t * noise_mul(unif01(k1a, k1b, (uint32_t)((n * 34 + m) * 32 + o)));
      vsm[m * 32 + o] = v;
      dp += fabsf(v);
    }
    red[mq * 32 + o] = dp;
    __syncthreads();
    for (int idx = tid; idx < 33 * 32; idx += 256) {
      int oo = idx & 31;
      float den = 1e-10f;
#pragma unroll
      for (int q = 0; q < 8; ++q) den += red[q * 32 + oo];
      S1s[idx] = vsm[idx] / den;
    }
    __syncthreads();
    const float* xp = x + (size_t)((n * 32 + b) * 32) * 256;
    float acc[32];
#pragma unroll
    for (int oo = 0; oo < 32; ++oo) acc[oo] = S1s[32 * 32 + oo];
    for (int m = 0; m < 32; ++m) {
      float xm = xp[m * 256 + tid];
#pragma unroll
      for (int oo = 0; oo < 32; ++oo) acc[oo] += xm * S1s[m * 32 + oo];
    }
    float* ap = a1 + (size_t)((n * 32 + b) * 32) * 256;
#pragma unroll
    for (int oo = 0; oo < 32; ++oo)
      ap[oo * 256 + tid] = 0.05f + 0.5f * tanhf((acc[oo] - 0.3f) * 3.0f);
  } else if (bid < 672) {
    // ---- beta12: thread handles 8 t's for fixed (n,k), both cascades ----
    int u = (bid - 160) * 256 + tid;    // [0, 131072)
    int k = u & 1023;
    int tc = (u >> 10) & 31;
    int n = u >> 15;                    // 0..3
    float Rt1 = sigmoidf(Rlf[k * 2 + 0]) * (C_RMAX - C_RMIN) + C_RMIN;
    float Ct1 = sigmoidf(Clf[k * 2 + 0]) * (C_CMAX - C_CMIN) + C_CMIN;
    float Rt2 = sigmoidf(Rlf[k * 2 + 1]) * (C_RMAX - C_RMIN) + C_RMIN;
    float Ct2 = sigmoidf(Clf[k * 2 + 1]) * (C_CMAX - C_CMIN) + C_CMIN;
#pragma unroll
    for (int it = 0; it < 8; ++it) {
      int t = tc * 8 + it;
      uint32_t e = (uint32_t)((t * 1024 + k) * 4 + n);
      float nR1 = noise_mul(unif01(kR1a, kR1b, e));
      float nC1 = noise_mul(unif01(kC1a, kC1b, e));
      float mu1 = unif01(kM1a, kM1b, e) * C_COUP + 1.0f;
      float rc1 = mu1 * (Rt1 * nR1) * (Ct1 * nC1);
      float nR2 = noise_mul(unif01(kR2a, kR2b, e));
      float nC2 = noise_mul(unif01(kC2a, kC2b, e));
      float mu2 = unif01(kM2a, kM2b, e) * C_COUP + 1.0f;
      float rc2 = mu2 * (Rt2 * nR2) * (Ct2 * nC2);
      float2 bb = { rc1 / (rc1 + C_DT), rc2 / (rc2 + C_DT) };
      *(float2*)&beta12[(size_t)(((n * 256 + t) * 1024) + k) * 2] = bb;
    }
  } else {
    // ---- wbuf: 131072 raw bf16 weights in fragment layout, 4 per thread ----
#pragma unroll
    for (int i = 0; i < 4; ++i) {
      int widx = (bid - 672) * 1024 + i * 256 + tid;   // [0, 131072)
      int grp = widx >> 12;             // n*8 + e
      int n = grp >> 3, e = grp & 7;
      int w4 = widx & 4095;
      int j = w4 & 7;
      int lane_ = (w4 >> 3) & 63;
      int ot = (w4 >> 9) & 1;
      int ks = w4 >> 10;                // 0..3
      int sub = ((lane_ >> 4) << 3) + j;
      int jrow = (e * 4 + ks) * 33 + 1 + sub;
      int oo = ot * 16 + (lane_ & 15);
      float th = theta_eff(theta2[jrow * 32 + oo]);
      float u = unif01(k4a, k4b, (uint32_t)((n * 1058 + jrow) * 32 + oo));
      float w = th * noise_mul(u);      // RAW: no /sden (applied in cb)
      uint32_t wb = __float_as_uint(w);
      wbuf[widx] = (uint16_t)((wb + 0x7FFFu + ((wb >> 16) & 1u)) >> 16);  // RNE
    }
  }
}

// ---------------------------------------------------------------------------
// FK10: fk8 (best-measured structure) with W loaded from wbuf instead of
// regenerated per block — the per-block 4096-threefry W build was ~6 us of
// redundant chip-wide VALU (32 b-blocks share each (n,e) W slice).
// No prefetch (R11: +10 us), no launch-bound min-waves. Grid/swizzle
// unchanged: bid = b*32 + n*8 + e; 192 thr; single RNE bf16 y-plane.
// ---------------------------------------------------------------------------
#define YP 136                      // uint16 per t-row (128 + 8 pad)
#define YPLANE (16 * YP)            // one chunk plane (uint16 count)

__global__ __launch_bounds__(192) void fk10_kernel(
    const float* __restrict__ a1, const uint16_t* __restrict__ wbuf,
    const float* __restrict__ beta12, float* __restrict__ zpart,
    uint32_t k01a, uint32_t k01b, uint32_t k02a, uint32_t k02b) {
  int bid = blockIdx.x;
  int g = bid & 31;                 // g = n*8 + e
  int b = bid >> 5;
  int n = g >> 3, e = g & 7;
  int nb = n * 32 + b;
  int tid = threadIdx.x;

  __shared__ __align__(16) uint16_t yh[2 * YPLANE];   // 8704 B
  __shared__ __align__(16) short wf[8 * 512];         // 8192 B

  const float* a1nb = a1 + (size_t)nb * 8192;
  const float* bp = beta12 + (size_t)n * 524288 + e * 256;
  float* zout = zpart + (size_t)bid * 8192;

  // W: copy 8 KB fragment slice global -> LDS (512 uint4)
  {
    const uint4* wsrc = (const uint4*)(wbuf + (size_t)g * 4096);
    uint4* wdst = (uint4*)wf;
    for (int i = tid; i < 512; i += 192) wdst[i] = wsrc[i];
  }

  float s1 = 0.0f, s2 = 0.0f;
  int cc = 0;
  if (tid < 128) {
    int k = e * 128 + tid;
    uint32_t e0 = (uint32_t)((k * 4 + n) * 32 + b);
    s1 = unif01(k01a, k01b, e0);
    s2 = unif01(k02a, k02b, e0);
    cc = k >> 5;
  }
  __syncthreads();

  for (int c = 0; c <= 16; ++c) {
    if (tid < 128) {
      if (c < 16) {
        uint16_t* yhb = yh + (c & 1) * YPLANE;
        int t0 = c * 16;
#pragma unroll
        for (int it = 0; it < 16; ++it) {
          int t = t0 + it;
          uint32_t sb = __float_as_uint(s2);
          uint32_t r = (sb + 0x7FFFu + ((sb >> 16) & 1u)) >> 16;  // RNE bf16
          yhb[it * YP + tid] = (uint16_t)r;
          float2 bb = *(const float2*)&bp[(size_t)t * 2048 + tid * 2];
          float xv = a1nb[cc * 256 + t];
          s2 = bb.y * (s2 - s1) + s1;     // cascade 2 eats pre-update s1
          s1 = bb.x * (s1 - xv) + xv;
        }
      }
    } else if (c >= 1) {
      int lane = tid - 128;
      int tc = lane & 15, q = lane >> 4;
      const uint16_t* yhr = yh + ((c - 1) & 1) * YPLANE + tc * YP + q * 8;
      floatx4 acc0a = {0,0,0,0}, acc0b = {0,0,0,0};
      floatx4 acc1a = {0,0,0,0}, acc1b = {0,0,0,0};
#pragma unroll
      for (int ks = 0; ks < 4; ++ks) {
        bf16x8 ah = *(const bf16x8*)(yhr + ks * 32);
        bf16x8 bh0 = *(const bf16x8*)&wf[(ks * 2 + 0) * 512 + lane * 8];
        bf16x8 bh1 = *(const bf16x8*)&wf[(ks * 2 + 1) * 512 + lane * 8];
        if (ks & 1) {
          acc0b = __builtin_amdgcn_mfma_f32_16x16x32_bf16(ah, bh0, acc0b, 0, 0, 0);
          acc1b = __builtin_amdgcn_mfma_f32_16x16x32_bf16(ah, bh1, acc1b, 0, 0, 0);
        } else {
          acc0a = __builtin_amdgcn_mfma_f32_16x16x32_bf16(ah, bh0, acc0a, 0, 0, 0);
          acc1a = __builtin_amdgcn_mfma_f32_16x16x32_bf16(ah, bh1, acc1a, 0, 0, 0);
        }
      }
      int t0 = (c - 1) * 16;
      floatx4 r0 = acc0a + acc0b;
      floatx4 r1 = acc1a + acc1b;
      // D layout: col = lane&15 (=o within tile), row = q*4 + reg (=t_local)
      *(floatx4*)&zout[tc * 256 + t0 + q * 4] = r0;
      *(floatx4*)&zout[(16 + tc) * 256 + t0 + q * 4] = r1;
    }
    __syncthreads();
  }
}

// ---------------------------------------------------------------------------
// CB4: combine 8 K-eighths (RAW — apply 1/sden[o] once), + direct-channel
// term + bias + activation. zpart slices at bid = b*32 + n*8 + e.
// ---------------------------------------------------------------------------
__global__ __launch_bounds__(256) void cb4_kernel(
    const float* __restrict__ a1, const float* __restrict__ theta2,
    const float* __restrict__ denom2p,
    const float* __restrict__ zpart, float* __restrict__ out,
    uint32_t k4a, uint32_t k4b) {
  int nb = blockIdx.x;
  int n = nb >> 5, b = nb & 31;
  int t = threadIdx.x;
  __shared__ float xs[32][256];
  __shared__ float wd[33 * 32];   // r<32: direct channel c=r (j=r*33); r=32: bias
  __shared__ float sden[32];
  __shared__ float rsd[32];
  if (t < 32) {
    float d = 1e-10f;
#pragma unroll
    for (int q = 0; q < 8; ++q) d += denom2p[(n * 8 + q) * 32 + t];
    sden[t] = d;
    rsd[t] = 1.0f / d;
  }
  const float* a1nb = a1 + (size_t)nb * 8192;
  for (int c = 0; c < 32; ++c) xs[c][t] = a1nb[c * 256 + t];
  __syncthreads();
  for (int idx = t; idx < 33 * 32; idx += 256) {
    int r = idx >> 5, oo = idx & 31;
    int j = (r < 32) ? r * 33 : 1056;
    float th = theta_eff(theta2[j * 32 + oo]);
    float u = unif01(k4a, k4b, (uint32_t)((n * 1058 + j) * 32 + oo));
    wd[idx] = th * noise_mul(u) / sden[oo];
  }
  __syncthreads();
  const float* zp = zpart + (size_t)(b * 32 + n * 8) * 8192;
  float* op = out + (size_t)nb * 8192;
  for (int o = 0; o < 32; ++o) {
    float z = wd[32 * 32 + o];
#pragma unroll
    for (int c = 0; c < 32; ++c) z += xs[c][t] * wd[c * 32 + o];
    float zf = 0.0f;
#pragma unroll
    for (int e = 0; e < 8; ++e) zf += zp[e * 8192 + o * 256 + t];
    z += zf * rsd[o];
    op[o * 256 + t] = 0.05f + 0.5f * tanhf((z - 0.3f) * 3.0f);
  }
}

// ---------------------------------------------------------------------------
// Launch
// ---------------------------------------------------------------------------
struct KeyPair { uint32_t a, b; };

// jax.random.split(key, 4), PARTITIONABLE (foldlike): key_i = threefry(key,(0,i))
static inline void split4_host(KeyPair key, KeyPair out[4]) {
  for (uint32_t i = 0; i < 4; ++i) {
    uint32_t x0 = 0u, x1 = i;
    tf2x32(key.a, key.b, x0, x1);
    out[i] = {x0, x1};
  }
}

extern "C" void kernel_launch(void* const* d_in, const int* in_sizes, int n_in,
                              void* d_out, int out_size, void* d_ws, size_t ws_size,
                              hipStream_t stream) {
  const float* x   = (const float*)d_in[0];   // (4,32,32,256)
  const float* th1 = (const float*)d_in[1];   // (34,32)
  const float* th2 = (const float*)d_in[2];   // (1058,32)
  const float* Rlf = (const float*)d_in[3];   // (32,32,2)
  const float* Clf = (const float*)d_in[4];   // (32,32,2)
  float* out = (float*)d_out;                 // (4,32,32,256)
  float* ws = (float*)d_ws;

  // workspace layout (floats)
  float* den2p  = ws;                  // 1024
  float* a1     = ws + 1024;           // 1048576
  float* beta12 = ws + 1049600;        // 2097152 (interleaved b1,b2)
  float* zpart  = ws + 3146752;        // 8388608 (1024 blocks x 8192)
  uint16_t* wbuf = (uint16_t*)(ws + 11535360);  // 131072 shorts (256 KB)

  KeyPair root{0u, 42u};
  KeyPair kk[4];  split4_host(root, kk);     // {k1, k2, k3, k4}
  KeyPair f1[4];  split4_host(kk[1], f1);    // {kR1, kC1, kmu1, k01}
  KeyPair f2[4];  split4_host(kk[2], f2);    // {kR2, kC2, kmu2, k02}

  prep_kernel<<<dim3(800), dim3(256), 0, stream>>>(
      Rlf, Clf, th1, th2, x, beta12, a1, den2p, wbuf,
      kk[0].a, kk[0].b, kk[3].a, kk[3].b,
      f1[0].a, f1[0].b, f1[1].a, f1[1].b, f1[2].a, f1[2].b,
      f2[0].a, f2[0].b, f2[1].a, f2[1].b, f2[2].a, f2[2].b);
  fk10_kernel<<<dim3(1024), dim3(192), 0, stream>>>(
      a1, wbuf, beta12, zpart,
      f1[3].a, f1[3].b, f2[3].a, f2[3].b);
  cb4_kernel<<<dim3(128), dim3(256), 0, stream>>>(
      a1, th2, den2p, zpart, out, kk[3].a, kk[3].b);
}

// Round 13
// 134.029 us; speedup vs baseline: 1.1454x; 1.0065x over previous
//
#include <hip/hip_runtime.h>
#include <stdint.h>

// ---------------------------------------------------------------------------
// Problem constants (from reference)
// ---------------------------------------------------------------------------
#define C_RMIN 100000.0f
#define C_RMAX 10000000.0f
#define C_CMIN 1e-07f
#define C_CMAX 1e-04f
#define C_DT   0.1f
#define C_EPS  0.05f
#define C_COUP 0.2f

typedef __attribute__((ext_vector_type(8))) short bf16x8;
typedef __attribute__((ext_vector_type(4))) float floatx4;

// ---------------------------------------------------------------------------
// Threefry-2x32 (exact JAX semantics). Host+device.
// ---------------------------------------------------------------------------
__host__ __device__ inline void tf2x32(uint32_t k0, uint32_t k1,
                                       uint32_t& x0, uint32_t& x1) {
  uint32_t ks2 = k0 ^ k1 ^ 0x1BD11BDAu;
  uint32_t a = x0 + k0, b = x1 + k1;
#define TFR(r) a += b; b = (b << (r)) | (b >> (32 - (r))); b ^= a;
  TFR(13) TFR(15) TFR(26) TFR(6)
  a += k1;  b += ks2 + 1u;
  TFR(17) TFR(29) TFR(16) TFR(24)
  a += ks2; b += k0 + 2u;
  TFR(13) TFR(15) TFR(26) TFR(6)
  a += k0;  b += k1 + 3u;
  TFR(17) TFR(29) TFR(16) TFR(24)
  a += k1;  b += ks2 + 4u;
  TFR(13) TFR(15) TFR(26) TFR(6)
  a += ks2; b += k0 + 5u;
#undef TFR
  x0 = a; x1 = b;
}

// jax.random.uniform element e, PARTITIONABLE threefry (jax>=0.5 default):
// one block per element, counter = (0, e), bits = out0 ^ out1.
__device__ inline float unif01(uint32_t k0, uint32_t k1, uint32_t e) {
  uint32_t x0 = 0u, x1 = e;
  tf2x32(k0, k1, x0, x1);
  uint32_t bits = x0 ^ x1;
  return __uint_as_float((bits >> 9) | 0x3F800000u) - 1.0f;
}

__device__ inline float theta_eff(float t) {
  t = fminf(fmaxf(t, -10.0f), 10.0f);
  return (fabsf(t) < 0.01f) ? 0.0f : t;
}

__device__ inline float sigmoidf(float x) { return 1.0f / (1.0f + expf(-x)); }

__device__ inline float noise_mul(float u) { return (u * 2.0f - 1.0f) * C_EPS + 1.0f; }

// ---------------------------------------------------------------------------
// PREP (single prep kernel, heavy-work-first):
//   bids [0,32)      -> denom2 partials (64-way j split)
//   bids [32,160)    -> a1 (first pmac), S1eff regenerated in-block
//   bids [160,1184)  -> beta12 interleaved; 4 t's/thread (2x finer than R12:
//                       threefry is issue-bound at ~40% efficiency — more
//                       waves/SIMD hide the 20-round serial dep chain)
//   bids [1184,1312) -> wbuf: RAW theta*noise as RNE bf16, fragment layout
//                       (no /sden — division commutes past the MFMA k-sum)
// ---------------------------------------------------------------------------
__global__ __launch_bounds__(256) void prep_kernel(
    const float* __restrict__ Rlf, const float* __restrict__ Clf,
    const float* __restrict__ theta1, const float* __restrict__ theta2,
    const float* __restrict__ x,
    float* __restrict__ beta12, float* __restrict__ a1,
    float* __restrict__ denom2p, uint16_t* __restrict__ wbuf,
    uint32_t k1a, uint32_t k1b, uint32_t k4a, uint32_t k4b,
    uint32_t kR1a, uint32_t kR1b, uint32_t kC1a, uint32_t kC1b,
    uint32_t kM1a, uint32_t kM1b,
    uint32_t kR2a, uint32_t kR2b, uint32_t kC2a, uint32_t kC2b,
    uint32_t kM2a, uint32_t kM2b) {
  __shared__ float red[256];
  __shared__ float vsm[34 * 32];
  __shared__ float S1s[33 * 32];
  int bid = blockIdx.x;
  int tid = threadIdx.x;
  if (bid < 32) {
    // ---- denom2 partials: denom2p[(n*8+p)*32+o] ----
    int n = bid >> 3, p = bid & 7;
    int o = tid & 31;
    int jc = tid >> 5;                  // 0..7
    int j0 = p * 8 + jc;                // 0..63
    float part = 0.0f;
    for (int j = j0; j < 1058; j += 64) {
      float t = theta_eff(theta2[j * 32 + o]);
      float u = unif01(k4a, k4b, (uint32_t)((n * 1058 + j) * 32 + o));
      part += fabsf(t * noise_mul(u));
    }
    red[jc * 32 + o] = part;
    __syncthreads();
    if (jc == 0) {
      float s = 0.0f;
      for (int q = 0; q < 8; ++q) s += red[q * 32 + o];
      denom2p[(n * 8 + p) * 32 + o] = s;
    }
  } else if (bid < 160) {
    // ---- a1[n][b][o][t], S1eff regenerated in-block, acc in registers ----
    int blk = bid - 32;
    int n = blk >> 5, b = blk & 31;
    int o = tid & 31, mq = tid >> 5;    // mq 0..7
    float dp = 0.0f;
    for (int m = mq; m < 34; m += 8) {
      float t = theta_eff(theta1[m * 32 + o]);
      float v = t * noise_mul(unif01(k1a, k1b, (uint32_t)((n * 34 + m) * 32 + o)));
      vsm[m * 32 + o] = v;
      dp += fabsf(v);
    }
    red[mq * 32 + o] = dp;
    __syncthreads();
    for (int idx = tid; idx < 33 * 32; idx += 256) {
      int oo = idx & 31;
      float den = 1e-10f;
#pragma unroll
      for (int q = 0; q < 8; ++q) den += red[q * 32 + oo];
      S1s[idx] = vsm[idx] / den;
    }
    __syncthreads();
    const float* xp = x + (size_t)((n * 32 + b) * 32) * 256;
    float acc[32];
#pragma unroll
    for (int oo = 0; oo < 32; ++oo) acc[oo] = S1s[32 * 32 + oo];
    for (int m = 0; m < 32; ++m) {
      float xm = xp[m * 256 + tid];
#pragma unroll
      for (int oo = 0; oo < 32; ++oo) acc[oo] += xm * S1s[m * 32 + oo];
    }
    float* ap = a1 + (size_t)((n * 32 + b) * 32) * 256;
#pragma unroll
    for (int oo = 0; oo < 32; ++oo)
      ap[oo * 256 + tid] = 0.05f + 0.5f * tanhf((acc[oo] - 0.3f) * 3.0f);
  } else if (bid < 1184) {
    // ---- beta12: thread handles 4 t's for fixed (n,k), both cascades ----
    int u = (bid - 160) * 256 + tid;    // [0, 262144)
    int k = u & 1023;
    int tc = (u >> 10) & 63;
    int n = u >> 16;                    // 0..3
    float Rt1 = sigmoidf(Rlf[k * 2 + 0]) * (C_RMAX - C_RMIN) + C_RMIN;
    float Ct1 = sigmoidf(Clf[k * 2 + 0]) * (C_CMAX - C_CMIN) + C_CMIN;
    float Rt2 = sigmoidf(Rlf[k * 2 + 1]) * (C_RMAX - C_RMIN) + C_RMIN;
    float Ct2 = sigmoidf(Clf[k * 2 + 1]) * (C_CMAX - C_CMIN) + C_CMIN;
#pragma unroll
    for (int it = 0; it < 4; ++it) {
      int t = tc * 4 + it;
      uint32_t e = (uint32_t)((t * 1024 + k) * 4 + n);
      float nR1 = noise_mul(unif01(kR1a, kR1b, e));
      float nC1 = noise_mul(unif01(kC1a, kC1b, e));
      float mu1 = unif01(kM1a, kM1b, e) * C_COUP + 1.0f;
      float rc1 = mu1 * (Rt1 * nR1) * (Ct1 * nC1);
      float nR2 = noise_mul(unif01(kR2a, kR2b, e));
      float nC2 = noise_mul(unif01(kC2a, kC2b, e));
      float mu2 = unif01(kM2a, kM2b, e) * C_COUP + 1.0f;
      float rc2 = mu2 * (Rt2 * nR2) * (Ct2 * nC2);
      float2 bb = { rc1 / (rc1 + C_DT), rc2 / (rc2 + C_DT) };
      *(float2*)&beta12[(size_t)(((n * 256 + t) * 1024) + k) * 2] = bb;
    }
  } else {
    // ---- wbuf: 131072 raw bf16 weights in fragment layout, 4 per thread ----
#pragma unroll
    for (int i = 0; i < 4; ++i) {
      int widx = (bid - 1184) * 1024 + i * 256 + tid;   // [0, 131072)
      int grp = widx >> 12;             // n*8 + e
      int n = grp >> 3, e = grp & 7;
      int w4 = widx & 4095;
      int j = w4 & 7;
      int lane_ = (w4 >> 3) & 63;
      int ot = (w4 >> 9) & 1;
      int ks = w4 >> 10;                // 0..3
      int sub = ((lane_ >> 4) << 3) + j;
      int jrow = (e * 4 + ks) * 33 + 1 + sub;
      int oo = ot * 16 + (lane_ & 15);
      float th = theta_eff(theta2[jrow * 32 + oo]);
      float u = unif01(k4a, k4b, (uint32_t)((n * 1058 + jrow) * 32 + oo));
      float w = th * noise_mul(u);      // RAW: no /sden (applied in cb)
      uint32_t wb = __float_as_uint(w);
      wbuf[widx] = (uint16_t)((wb + 0x7FFFu + ((wb >> 16) & 1u)) >> 16);  // RNE
    }
  }
}

// ---------------------------------------------------------------------------
// FK11: fk10 + current-chunk load batching. All 16 beta + 16 x loads issue
// at chunk top into locals (one ~200-cyc vmcnt wait instead of 16 serial
// stalls inside the FMA chain). Unlike R11's next-chunk prefetch, the arrays
// are NOT live across barriers -> no occupancy-killing register doubling.
// Grid/swizzle: bid = b*32 + n*8 + e; 192 thr; single RNE bf16 y-plane;
// W loaded from wbuf (R12 win).
// ---------------------------------------------------------------------------
#define YP 136                      // uint16 per t-row (128 + 8 pad)
#define YPLANE (16 * YP)            // one chunk plane (uint16 count)

__global__ __launch_bounds__(192) void fk11_kernel(
    const float* __restrict__ a1, const uint16_t* __restrict__ wbuf,
    const float* __restrict__ beta12, float* __restrict__ zpart,
    uint32_t k01a, uint32_t k01b, uint32_t k02a, uint32_t k02b) {
  int bid = blockIdx.x;
  int g = bid & 31;                 // g = n*8 + e
  int b = bid >> 5;
  int n = g >> 3, e = g & 7;
  int nb = n * 32 + b;
  int tid = threadIdx.x;

  __shared__ __align__(16) uint16_t yh[2 * YPLANE];   // 8704 B
  __shared__ __align__(16) short wf[8 * 512];         // 8192 B

  const float* a1nb = a1 + (size_t)nb * 8192;
  const float* bp = beta12 + (size_t)n * 524288 + e * 256;
  float* zout = zpart + (size_t)bid * 8192;

  // W: copy 8 KB fragment slice global -> LDS (512 uint4)
  {
    const uint4* wsrc = (const uint4*)(wbuf + (size_t)g * 4096);
    uint4* wdst = (uint4*)wf;
    for (int i = tid; i < 512; i += 192) wdst[i] = wsrc[i];
  }

  float s1 = 0.0f, s2 = 0.0f;
  int cc = 0;
  if (tid < 128) {
    int k = e * 128 + tid;
    uint32_t e0 = (uint32_t)((k * 4 + n) * 32 + b);
    s1 = unif01(k01a, k01b, e0);
    s2 = unif01(k02a, k02b, e0);
    cc = k >> 5;
  }
  __syncthreads();

  for (int c = 0; c <= 16; ++c) {
    if (tid < 128) {
      if (c < 16) {
        int t0 = c * 16;
        // batch ALL of this chunk's loads before the serial FMA chain
        float2 bloc[16];
        float xloc[16];
#pragma unroll
        for (int it = 0; it < 16; ++it) {
          bloc[it] = *(const float2*)&bp[(size_t)(t0 + it) * 2048 + tid * 2];
          xloc[it] = a1nb[cc * 256 + t0 + it];
        }
        uint16_t* yhb = yh + (c & 1) * YPLANE;
#pragma unroll
        for (int it = 0; it < 16; ++it) {
          uint32_t sb = __float_as_uint(s2);
          uint32_t r = (sb + 0x7FFFu + ((sb >> 16) & 1u)) >> 16;  // RNE bf16
          yhb[it * YP + tid] = (uint16_t)r;
          float2 bb = bloc[it];
          float xv = xloc[it];
          s2 = bb.y * (s2 - s1) + s1;     // cascade 2 eats pre-update s1
          s1 = bb.x * (s1 - xv) + xv;
        }
      }
    } else if (c >= 1) {
      int lane = tid - 128;
      int tc = lane & 15, q = lane >> 4;
      const uint16_t* yhr = yh + ((c - 1) & 1) * YPLANE + tc * YP + q * 8;
      floatx4 acc0a = {0,0,0,0}, acc0b = {0,0,0,0};
      floatx4 acc1a = {0,0,0,0}, acc1b = {0,0,0,0};
#pragma unroll
      for (int ks = 0; ks < 4; ++ks) {
        bf16x8 ah = *(const bf16x8*)(yhr + ks * 32);
        bf16x8 bh0 = *(const bf16x8*)&wf[(ks * 2 + 0) * 512 + lane * 8];
        bf16x8 bh1 = *(const bf16x8*)&wf[(ks * 2 + 1) * 512 + lane * 8];
        if (ks & 1) {
          acc0b = __builtin_amdgcn_mfma_f32_16x16x32_bf16(ah, bh0, acc0b, 0, 0, 0);
          acc1b = __builtin_amdgcn_mfma_f32_16x16x32_bf16(ah, bh1, acc1b, 0, 0, 0);
        } else {
          acc0a = __builtin_amdgcn_mfma_f32_16x16x32_bf16(ah, bh0, acc0a, 0, 0, 0);
          acc1a = __builtin_amdgcn_mfma_f32_16x16x32_bf16(ah, bh1, acc1a, 0, 0, 0);
        }
      }
      int t0 = (c - 1) * 16;
      floatx4 r0 = acc0a + acc0b;
      floatx4 r1 = acc1a + acc1b;
      // D layout: col = lane&15 (=o within tile), row = q*4 + reg (=t_local)
      *(floatx4*)&zout[tc * 256 + t0 + q * 4] = r0;
      *(floatx4*)&zout[(16 + tc) * 256 + t0 + q * 4] = r1;
    }
    __syncthreads();
  }
}

// ---------------------------------------------------------------------------
// CB4: combine 8 K-eighths (RAW — apply 1/sden[o] once), + direct-channel
// term + bias + activation. zpart slices at bid = b*32 + n*8 + e.
// ---------------------------------------------------------------------------
__global__ __launch_bounds__(256) void cb4_kernel(
    const float* __restrict__ a1, const float* __restrict__ theta2,
    const float* __restrict__ denom2p,
    const float* __restrict__ zpart, float* __restrict__ out,
    uint32_t k4a, uint32_t k4b) {
  int nb = blockIdx.x;
  int n = nb >> 5, b = nb & 31;
  int t = threadIdx.x;
  __shared__ float xs[32][256];
  __shared__ float wd[33 * 32];   // r<32: direct channel c=r (j=r*33); r=32: bias
  __shared__ float sden[32];
  __shared__ float rsd[32];
  if (t < 32) {
    float d = 1e-10f;
#pragma unroll
    for (int q = 0; q < 8; ++q) d += denom2p[(n * 8 + q) * 32 + t];
    sden[t] = d;
    rsd[t] = 1.0f / d;
  }
  const float* a1nb = a1 + (size_t)nb * 8192;
  for (int c = 0; c < 32; ++c) xs[c][t] = a1nb[c * 256 + t];
  __syncthreads();
  for (int idx = t; idx < 33 * 32; idx += 256) {
    int r = idx >> 5, oo = idx & 31;
    int j = (r < 32) ? r * 33 : 1056;
    float th = theta_eff(theta2[j * 32 + oo]);
    float u = unif01(k4a, k4b, (uint32_t)((n * 1058 + j) * 32 + oo));
    wd[idx] = th * noise_mul(u) / sden[oo];
  }
  __syncthreads();
  const float* zp = zpart + (size_t)(b * 32 + n * 8) * 8192;
  float* op = out + (size_t)nb * 8192;
  for (int o = 0; o < 32; ++o) {
    float z = wd[32 * 32 + o];
#pragma unroll
    for (int c = 0; c < 32; ++c) z += xs[c][t] * wd[c * 32 + o];
    float zf = 0.0f;
#pragma unroll
    for (int e = 0; e < 8; ++e) zf += zp[e * 8192 + o * 256 + t];
    z += zf * rsd[o];
    op[o * 256 + t] = 0.05f + 0.5f * tanhf((z - 0.3f) * 3.0f);
  }
}

// ---------------------------------------------------------------------------
// Launch
// ---------------------------------------------------------------------------
struct KeyPair { uint32_t a, b; };

// jax.random.split(key, 4), PARTITIONABLE (foldlike): key_i = threefry(key,(0,i))
static inline void split4_host(KeyPair key, KeyPair out[4]) {
  for (uint32_t i = 0; i < 4; ++i) {
    uint32_t x0 = 0u, x1 = i;
    tf2x32(key.a, key.b, x0, x1);
    out[i] = {x0, x1};
  }
}

extern "C" void kernel_launch(void* const* d_in, const int* in_sizes, int n_in,
                              void* d_out, int out_size, void* d_ws, size_t ws_size,
                              hipStream_t stream) {
  const float* x   = (const float*)d_in[0];   // (4,32,32,256)
  const float* th1 = (const float*)d_in[1];   // (34,32)
  const float* th2 = (const float*)d_in[2];   // (1058,32)
  const float* Rlf = (const float*)d_in[3];   // (32,32,2)
  const float* Clf = (const float*)d_in[4];   // (32,32,2)
  float* out = (float*)d_out;                 // (4,32,32,256)
  float* ws = (float*)d_ws;

  // workspace layout (floats)
  float* den2p  = ws;                  // 1024
  float* a1     = ws + 1024;           // 1048576
  float* beta12 = ws + 1049600;        // 2097152 (interleaved b1,b2)
  float* zpart  = ws + 3146752;        // 8388608 (1024 blocks x 8192)
  uint16_t* wbuf = (uint16_t*)(ws + 11535360);  // 131072 shorts (256 KB)

  KeyPair root{0u, 42u};
  KeyPair kk[4];  split4_host(root, kk);     // {k1, k2, k3, k4}
  KeyPair f1[4];  split4_host(kk[1], f1);    // {kR1, kC1, kmu1, k01}
  KeyPair f2[4];  split4_host(kk[2], f2);    // {kR2, kC2, kmu2, k02}

  prep_kernel<<<dim3(1312), dim3(256), 0, stream>>>(
      Rlf, Clf, th1, th2, x, beta12, a1, den2p, wbuf,
      kk[0].a, kk[0].b, kk[3].a, kk[3].b,
      f1[0].a, f1[0].b, f1[1].a, f1[1].b, f1[2].a, f1[2].b,
      f2[0].a, f2[0].b, f2[1].a, f2[1].b, f2[2].a, f2[2].b);
  fk11_kernel<<<dim3(1024), dim3(192), 0, stream>>>(
      a1, wbuf, beta12, zpart,
      f1[3].a, f1[3].b, f2[3].a, f2[3].b);
  cb4_kernel<<<dim3(128), dim3(256), 0, stream>>>(
      a1, th2, den2p, zpart, out, kk[3].a, kk[3].b);
}